// Round 1
// baseline (424.263 us; speedup 1.0000x reference)
//
#include <hip/hip_runtime.h>

#define NGRID 8192
#define NLAYER 24
#define NPERIODS 50
#define NOBS 4096
#define NC 200
#define PP 64            // periods padded to 64
#define NSPLIT 8         // g-splits across blockIdx.y
#define NBINS 1024
#define OTILE 64
#define KG 32            // g subtile staged in LDS
#define VREF 3.0f

// ---------------- K0: zero the atomic bins ----------------
__global__ void k0_zero(float* __restrict__ bins) {
    bins[threadIdx.x] = 0.f;
}

// ---------------- K1: r_pad[g][p] = 1/(0.92 * sum_l w[p][l]*Vs[g][l]) ----------------
__global__ __launch_bounds__(256) void k1_rpad(const float* __restrict__ Vs,
                                               const float* __restrict__ thick,
                                               const float* __restrict__ periods,
                                               float* __restrict__ r_pad) {
    __shared__ float w_sh[NLAYER][NPERIODS];   // transposed: reads are conflict-free
    __shared__ float z_sh[NLAYER];
    int tid = threadIdx.x;
    if (tid < NLAYER) {
        float c = 0.f;
        for (int i = 0; i <= tid; ++i) c += thick[i];
        z_sh[tid] = c - 0.5f * thick[tid];
    }
    __syncthreads();
    if (tid < NPERIODS) {
        float ds = (VREF / 3.0f) * periods[tid];
        float tmp[NLAYER];
        float s = 0.f;
        #pragma unroll
        for (int l = 0; l < NLAYER; ++l) {
            float v = expf(-z_sh[l] / ds) * thick[l];
            tmp[l] = v; s += v;
        }
        float inv = 1.f / s;
        #pragma unroll
        for (int l = 0; l < NLAYER; ++l) w_sh[l][tid] = tmp[l] * inv;
    }
    __syncthreads();
    int idx = blockIdx.x * 256 + tid;          // idx = g*64 + p  (lanes share g -> broadcast Vs)
    int g = idx >> 6, p = idx & 63;
    float r = 0.f;
    if (p < NPERIODS) {
        const float4* vp = (const float4*)(Vs + (size_t)g * NLAYER);
        float s = 0.f;
        #pragma unroll
        for (int q = 0; q < NLAYER / 4; ++q) {
            float4 t = vp[q];
            s = fmaf(w_sh[4*q+0][p], t.x, s);
            s = fmaf(w_sh[4*q+1][p], t.y, s);
            s = fmaf(w_sh[4*q+2][p], t.z, s);
            s = fmaf(w_sh[4*q+3][p], t.w, s);
        }
        r = 1.0f / (0.92f * s);
    }
    r_pad[idx] = r;                            // fully coalesced, zero-padded p>=50
}

// ---------------- K2: partial[s][o][p] = sum_{g in split s} A[o][g]*r[g][p] ----------------
// lane <-> obs (64 obs/wave), 50 accumulators/lane in VGPRs.
// r[g][p] is wave-uniform -> scalar loads (SMEM), inner loop = v_fmac with SGPR operand.
// 4 waves/block take 4 g-subsplits of the same 64 obs; LDS cross-wave reduce.
__global__ __launch_bounds__(256) void k2_gemm(const float* __restrict__ A,
                                               const float* __restrict__ r_pad,
                                               float* __restrict__ partial) {
    __shared__ float lds[4 * OTILE * 36];      // per-wave A tile, stride 36 (b128-aligned, conflict-free)
    int tid  = threadIdx.x;
    int lane = tid & 63;
    int wv   = __builtin_amdgcn_readfirstlane(tid >> 6);  // keep uniform for s_load of r
    int o_base = blockIdx.x * OTILE;
    int split  = blockIdx.y;
    float* Aw = lds + wv * (OTILE * 36);

    float acc[NPERIODS];
    #pragma unroll
    for (int p = 0; p < NPERIODS; ++p) acc[p] = 0.f;

    const int GC = NGRID / (NSPLIT * 4);       // 256 g per wave
    int g_wave = (split * 4 + wv) * GC;

    for (int kt = 0; kt < GC / KG; ++kt) {     // 8 subtiles of 32 g
        int g0 = g_wave + kt * KG;
        // stage 64 obs x 32 g: 8 float4 per lane, 128B-contiguous per 8 lanes
        #pragma unroll
        for (int s = 0; s < 8; ++s) {
            int f   = s * 64 + lane;
            int row = f >> 3;
            int c4  = (f & 7) * 4;
            float4 t = *(const float4*)(A + (size_t)(o_base + row) * NGRID + g0 + c4);
            *(float4*)(Aw + row * 36 + c4) = t;
        }
        __syncthreads();
        #pragma unroll 1
        for (int gg = 0; gg < KG; gg += 4) {
            float4 a4 = *(const float4*)(Aw + lane * 36 + gg);
            const float* rr = r_pad + (size_t)(g0 + gg) * PP;
            #pragma unroll
            for (int j = 0; j < 4; ++j) {
                float aj = (j == 0) ? a4.x : (j == 1) ? a4.y : (j == 2) ? a4.z : a4.w;
                const float* rj = rr + j * PP;  // uniform address -> s_load
                #pragma unroll
                for (int p = 0; p < NPERIODS; ++p) acc[p] = fmaf(aj, rj[p], acc[p]);
            }
        }
        __syncthreads();
    }

    // cross-wave reduce (4 waves hold 4 g-chunks of the same obs), two 32-wide p halves
    float* outp = partial + (size_t)split * (NOBS * PP) + (size_t)o_base * PP;
    #pragma unroll
    for (int h = 0; h < 2; ++h) {
        __syncthreads();
        float* rw = lds + wv * (OTILE * 33);   // stride 33 -> conflict-free
        #pragma unroll
        for (int q = 0; q < 32; ++q) {
            int p = h * 32 + q;
            rw[lane * 33 + q] = (p < NPERIODS) ? acc[p] : 0.f;
        }
        __syncthreads();
        for (int e = tid; e < OTILE * 32; e += 256) {
            int oo = e >> 5, q = e & 31;
            float v = 0.f;
            #pragma unroll
            for (int w2 = 0; w2 < 4; ++w2) v += lds[w2 * (OTILE * 33) + oo * 33 + q];
            outp[oo * PP + h * 32 + q] = v;
        }
    }
}

// ---------------- K3: per (o,p) pair: max, searchsorted, interp, partial sum ----------------
__global__ __launch_bounds__(256) void k3_main(const float* __restrict__ energy,
                                               const float* __restrict__ c_axis,
                                               const float* __restrict__ partial,
                                               float* __restrict__ bins) {
    __shared__ float red[4];
    int tid  = threadIdx.x;
    int lane = tid & 63;
    int wv   = tid >> 6;
    int pair = blockIdx.x * 4 + wv;            // o-major: consecutive waves share c_axis row
    int o = pair / NPERIODS;
    int p = pair - o * NPERIODS;

    // s_pred = sum of 8 split partials
    float sp = 0.f;
    if (lane < NSPLIT) sp = partial[(size_t)lane * (NOBS * PP) + (size_t)o * PP + p];
    #pragma unroll
    for (int m = 32; m; m >>= 1) sp += __shfl_xor(sp, m, 64);
    float cp = 1.0f / sp;

    const float* erow = energy + ((size_t)o * NPERIODS + p) * NC;
    const float* crow = c_axis + (size_t)o * NC;
    float cnt = 0.f, mx = -1e30f;
    if (lane < NC / 4) {
        float4 e  = *(const float4*)(erow + 4 * lane);
        float4 ca = *(const float4*)(crow + 4 * lane);
        mx  = fmaxf(fmaxf(e.x, e.y), fmaxf(e.z, e.w));
        cnt = (ca.x < cp ? 1.f : 0.f) + (ca.y < cp ? 1.f : 0.f)
            + (ca.z < cp ? 1.f : 0.f) + (ca.w < cp ? 1.f : 0.f);
    }
    #pragma unroll
    for (int m = 32; m; m >>= 1) {
        cnt += __shfl_xor(cnt, m, 64);
        mx   = fmaxf(mx, __shfl_xor(mx, m, 64));
    }
    int idx = (int)cnt;                        // searchsorted 'left' = count(a < v)
    idx = idx < 1 ? 1 : (idx > NC - 1 ? NC - 1 : idx);
    float c0 = crow[idx - 1], c1 = crow[idx];  // broadcast (L1 hit)
    float e0 = erow[idx - 1], e1 = erow[idx];
    float wgt = (cp - c0) / (c1 - c0 + 1e-12f);
    float ei  = fmaf(wgt, e1 - e0, e0);
    float contrib = mx - ei;

    if (lane == 0) red[wv] = contrib;
    __syncthreads();
    if (tid == 0)
        atomicAdd(&bins[blockIdx.x & (NBINS - 1)], red[0] + red[1] + red[2] + red[3]);
}

// ---------------- K4: final reduce of bins -> out ----------------
__global__ __launch_bounds__(256) void k4_final(const float* __restrict__ bins,
                                                float* __restrict__ out) {
    __shared__ float red[4];
    int tid = threadIdx.x;
    float s = 0.f;
    for (int i = tid; i < NBINS; i += 256) s += bins[i];
    #pragma unroll
    for (int m = 32; m; m >>= 1) s += __shfl_xor(s, m, 64);
    int lane = tid & 63, wv = tid >> 6;
    if (lane == 0) red[wv] = s;
    __syncthreads();
    if (tid == 0) out[0] = -(red[0] + red[1] + red[2] + red[3]);  // / SIGMA^2 == 1
}

extern "C" void kernel_launch(void* const* d_in, const int* in_sizes, int n_in,
                              void* d_out, int out_size, void* d_ws, size_t ws_size,
                              hipStream_t stream) {
    const float* Vs      = (const float*)d_in[0];
    const float* A       = (const float*)d_in[1];
    const float* energy  = (const float*)d_in[2];
    const float* c_axis  = (const float*)d_in[3];
    const float* thick   = (const float*)d_in[4];
    const float* periods = (const float*)d_in[5];
    float* out = (float*)d_out;

    float* ws      = (float*)d_ws;
    float* r_pad   = ws;                                   // 8192*64  = 2 MB
    float* partial = r_pad + (size_t)NGRID * PP;           // 8*4096*64 = 8 MB
    float* bins    = partial + (size_t)NSPLIT * NOBS * PP; // 4 KB

    hipLaunchKernelGGL(k0_zero, dim3(1), dim3(NBINS), 0, stream, bins);
    hipLaunchKernelGGL(k1_rpad, dim3((NGRID * PP) / 256), dim3(256), 0, stream,
                       Vs, thick, periods, r_pad);
    hipLaunchKernelGGL(k2_gemm, dim3(NOBS / OTILE, NSPLIT), dim3(256), 0, stream,
                       A, r_pad, partial);
    hipLaunchKernelGGL(k3_main, dim3((NOBS * NPERIODS) / 4), dim3(256), 0, stream,
                       energy, c_axis, partial, bins);
    hipLaunchKernelGGL(k4_final, dim3(1), dim3(256), 0, stream, bins, out);
}